// Round 7
// baseline (6162.560 us; speedup 1.0000x reference)
//
#include <hip/hip_runtime.h>
#include <math.h>

static constexpr int Tc = 128, Vc = 97;

// ---- f32 weight tables in ws (floats) ----
static constexpr size_t T_FQ  = 0;                          // [576][1536] fused (Wqkv@W_in)^T, j contig
static constexpr size_t BF    = T_FQ + (size_t)576*1536;    // 1536 fused qkv bias
static constexpr size_t T_IN  = BF + 1536;                  // [576][512]  W_in^T
static constexpr size_t T_O   = T_IN + (size_t)576*512;     // [512][512]  e-major
static constexpr size_t T_FF1 = T_O + (size_t)512*512;      // [512][2048] d-major
static constexpr size_t T_FF2 = T_FF1 + (size_t)512*2048;   // [2048][512] k-major
static constexpr size_t T_TOK = T_FF2 + (size_t)2048*512;   // [512][128] col 16q+i -> vocab 13q+i
static constexpr size_t T_RW  = T_TOK + (size_t)512*128;    // [512][288] col 36q+i -> row 34q+i
static constexpr size_t ARENA = T_RW + (size_t)512*288;
static constexpr size_t TEAM_STRIDE = 8704;
static constexpr size_t A_YP = 0;        // 8*512 y partials
static constexpr size_t A_OP = 4096;     // 8*512 o partials
static constexpr size_t A_RWP = 8192;    // 272
static constexpr size_t FLG = ARENA + (size_t)32*TEAM_STRIDE; // 32*1024 ints

__device__ __forceinline__ float softplusf_(float x) { return x > 20.f ? x : log1pf(expf(x)); }
__device__ __forceinline__ float sigmoidf_(float x) { return 1.f / (1.f + expf(-x)); }

__device__ __forceinline__ float wsum(float v) {
#pragma unroll
  for (int o = 1; o < 64; o <<= 1) v += __shfl_xor(v, o);
  return v;
}
__device__ __forceinline__ float wmax(float v) {
#pragma unroll
  for (int o = 1; o < 64; o <<= 1) v = fmaxf(v, __shfl_xor(v, o));
  return v;
}

// LLC-coherent (system-scope, relaxed): sc0 sc1 -> bypass L1/L2, hit Infinity Cache
__device__ __forceinline__ void st_llc(float* p, float v) {
  __hip_atomic_store(p, v, __ATOMIC_RELAXED, __HIP_MEMORY_SCOPE_SYSTEM);
}
__device__ __forceinline__ float ld_llc(const float* p) {
  return __hip_atomic_load(p, __ATOMIC_RELAXED, __HIP_MEMORY_SCOPE_SYSTEM);
}
__device__ __forceinline__ void st_flag(int* p, int v) {
  __hip_atomic_store(p, v, __ATOMIC_RELAXED, __HIP_MEMORY_SCOPE_SYSTEM);
}
__device__ __forceinline__ int ld_flag(const int* p) {
  return __hip_atomic_load(p, __ATOMIC_RELAXED, __HIP_MEMORY_SCOPE_SYSTEM);
}

#define PUBF(stage)                                                      \
  do {                                                                   \
    asm volatile("s_waitcnt vmcnt(0)" ::: "memory");                     \
    __syncthreads();                                                     \
    if (tid == 0) st_flag(flg + (stage)*128 + sq*16, t + 1);             \
  } while (0)

// parallel poll: lanes 0..7 each watch one producer's flag
#define WAITF(stage, need)                                               \
  do {                                                                   \
    if (tid < 8) {                                                       \
      while (ld_flag(flg + (stage)*128 + tid*16) < (need))               \
        __builtin_amdgcn_s_sleep(1);                                     \
    }                                                                    \
    __syncthreads();                                                     \
    asm volatile("" ::: "memory");                                       \
  } while (0)

// generic split-K float4 matvec: NCH chunks of CH inputs, NG col-groups (x4 outputs)
template <int NCH, int CH, int NG, int SF4>
__device__ __forceinline__ void mvp(const float* __restrict__ wbase,
                                    const float* __restrict__ src,
                                    float* part, int tid) {
  const int cs = tid / NG, g = tid % NG;
  const float4* __restrict__ w4 =
      reinterpret_cast<const float4*>(wbase + (size_t)cs * CH * (SF4 * 4)) + g;
  const float* __restrict__ v = src + cs * CH;
  float a0 = 0.f, a1 = 0.f, a2 = 0.f, a3 = 0.f;
#pragma unroll 8
  for (int c = 0; c < CH; ++c) {
    float4 w = w4[(size_t)c * SF4];
    float vv = v[c];
    a0 += vv * w.x; a1 += vv * w.y; a2 += vv * w.z; a3 += vv * w.w;
  }
  *reinterpret_cast<float4*>(part + tid * 4) = make_float4(a0, a1, a2, a3);
}

// ---------------- init: transposes + remaps + fused bias + arena/flag zero ----------------
__global__ __launch_bounds__(256) void k_init(const float* __restrict__ W_in,
                                              const float* __restrict__ W_qkv,
                                              const float* __restrict__ W_o,
                                              const float* __restrict__ W_ff1,
                                              const float* __restrict__ W_ff2,
                                              const float* __restrict__ W_tok,
                                              const float* __restrict__ W_read,
                                              const float* __restrict__ W_write,
                                              const float* __restrict__ b_qkv,
                                              const float* __restrict__ b_in,
                                              float* __restrict__ ws) {
  const size_t tid = (size_t)blockIdx.x * 256 + threadIdx.x;
  const size_t nth = (size_t)gridDim.x * 256;
  for (size_t i = tid; i < (size_t)576*512; i += nth) {
    size_t c = i >> 9, j = i & 511;
    ws[T_IN + i] = W_in[j * 576 + c];
  }
  for (size_t i = tid; i < (size_t)512*512; i += nth) {
    size_t e = i >> 9, j = i & 511;
    ws[T_O + i] = W_o[j * 512 + e];
  }
  for (size_t i = tid; i < (size_t)512*2048; i += nth) {
    size_t d = i >> 11, f = i & 2047;
    ws[T_FF1 + i] = W_ff1[f * 512 + d];
  }
  for (size_t i = tid; i < (size_t)2048*512; i += nth) {
    size_t k = i >> 9, j = i & 511;
    ws[T_FF2 + i] = W_ff2[j * 2048 + k];
  }
  for (size_t i = tid; i < (size_t)512*128; i += nth) {
    size_t d = i >> 7, j = i & 127;
    int qq = (int)(j >> 4), i2 = (int)(j & 15);
    int v = qq * 13 + i2;
    ws[T_TOK + i] = (i2 < 13 && v < 97) ? W_tok[(size_t)v * 512 + d] : 0.f;
  }
  for (size_t i = tid; i < (size_t)512*288; i += nth) {
    size_t d = i / 288, j = i % 288;
    int qq = (int)(j / 36), i2 = (int)(j % 36);
    int idx = qq * 34 + i2;
    float val = 0.f;
    if (i2 < 34 && idx < 268)
      val = (idx < 70) ? W_read[(size_t)idx * 512 + d] : W_write[(size_t)(idx - 70) * 512 + d];
    ws[T_RW + i] = val;
  }
  for (size_t j = tid; j < 1536; j += nth) {
    float a = b_qkv[j];
    const float* r = W_qkv + j * 512;
    for (int d = 0; d < 512; ++d) a += r[d] * b_in[d];
    ws[BF + j] = a;
  }
  for (size_t i = tid; i < (size_t)32 * TEAM_STRIDE; i += nth) ws[ARENA + i] = 0.f;
  for (size_t i = tid; i < 32768; i += nth) ((int*)(ws + FLG))[i] = 0;
}

// ---------------- fused weight: T_FQ[c][j] = sum_d W_in[d][c]*W_qkv[j][d] ----------------
__global__ __launch_bounds__(256) void k_fuse(const float* __restrict__ W_qkv,
                                              const float* __restrict__ W_in,
                                              float* __restrict__ ws) {
  __shared__ float As[32][64];   // W_in[d][c]
  __shared__ float Bs[32][96];   // W_qkv[j][d] (transposed)
  const int cb = blockIdx.x % 9, jb = blockIdx.x / 9;
  const int c0 = cb * 64, j0 = jb * 96;
  const int tid = threadIdx.x;
  float acc[24];
#pragma unroll
  for (int u = 0; u < 24; ++u) acc[u] = 0.f;
  for (int d0 = 0; d0 < 512; d0 += 32) {
    __syncthreads();
    for (int i = tid; i < 32 * 64; i += 256) { int dd = i >> 6, cc = i & 63; As[dd][cc] = W_in[(size_t)(d0 + dd) * 576 + c0 + cc]; }
    for (int i = tid; i < 32 * 96; i += 256) { int jj = i >> 5, dd = i & 31; Bs[dd][jj] = W_qkv[(size_t)(j0 + jj) * 512 + d0 + dd]; }
    __syncthreads();
    const int tc = tid & 63, jbase = (tid >> 6) * 24;
    for (int dd = 0; dd < 32; ++dd) {
      float a = As[dd][tc];
#pragma unroll
      for (int u = 0; u < 24; ++u) acc[u] += a * Bs[dd][jbase + u];
    }
  }
  const int tc = tid & 63, jbase = (tid >> 6) * 24;
#pragma unroll
  for (int u = 0; u < 24; ++u)
    ws[T_FQ + (size_t)(c0 + tc) * 1536 + j0 + jbase + u] = acc[u];
}

// ---------------- team kernel: 8 wgs per batch, wg = b*8 + q (q = XCD slice) ----------------
__global__ __launch_bounds__(512) void k_main(
    const int* __restrict__ x, const float* __restrict__ emb,
    const float* __restrict__ b_in, const float* __restrict__ b_o,
    const float* __restrict__ ln1g, const float* __restrict__ ln1b,
    const float* __restrict__ b_ff1, const float* __restrict__ b_ff2,
    const float* __restrict__ ln2g, const float* __restrict__ ln2b,
    const float* __restrict__ b_tok,
    const float* __restrict__ b_read, const float* __restrict__ b_write,
    float* __restrict__ ws, float* __restrict__ dout) {
  const float* __restrict__ wt = ws;
  const int wg = blockIdx.x, tid = threadIdx.x;
  const int sq = wg & 7, b = wg >> 3;
  const int wv = tid >> 6, ln = tid & 63;
  float* ar = ws + ARENA + (size_t)b * TEAM_STRIDE;
  int* flg = (int*)(ws + FLG) + b * 1024;

  __shared__ float memS[128 * 64];           // FULL NTM memory, replicated
  __shared__ float kcS[8 * 64], vcS[8 * 64]; // own head's KV cache
  __shared__ float rwvS[128], wwvS[128], wwnS[128];
  __shared__ float rvec[64];
  __shared__ float wideS[576];
  __shared__ float xpSl[64];                 // own xp slice (residual)
  __shared__ float qhS[64];
  __shared__ float scoresS[8], awS[8];
  __shared__ float ctxH[64];
  __shared__ float yS[512], x2S[512], oS[512], onS[512];
  __shared__ float hSl[256];
  __shared__ __align__(16) float part[2048];
  __shared__ float rwpS[272];
  __shared__ float cosS[256];                // [0..127]=R, [128..255]=W
  __shared__ float redA[8], redB[8];
  __shared__ float eS[64], aS[64];

  for (int i = tid; i < 8192; i += 512) memS[i] = 0.f;
  if (tid < 128) { float v0 = (tid == 0) ? 1.f : 0.f; rwvS[tid] = v0; wwvS[tid] = v0; }
  __syncthreads();

  for (int t = 0; t < Tc; ++t) {
    // ---- r = rwv . mem (local, replicated state) ----
    {
      float a = 0.f;
#pragma unroll
      for (int k2 = 0; k2 < 16; ++k2) { int n = wv * 16 + k2; a += rwvS[n] * memS[n * 64 + ln]; }
      part[wv * 64 + ln] = a;
    }
    __syncthreads();
    if (tid < 64) {
      float s = 0.f;
#pragma unroll
      for (int p = 0; p < 8; ++p) s += part[p * 64 + tid];
      rvec[tid] = s;
    }
    __syncthreads();
    const int tok = x[b * Tc + t];
    for (int i = tid; i < 576; i += 512)
      wideS[i] = (i < 512) ? emb[(size_t)tok * 512 + i] : rvec[i - 512];
    __syncthreads();

    // ---- fused q/k/v for own head (from wide) ----
    const int slot = t & 7;
    for (int p3 = 0; p3 < 3; ++p3) {
      mvp<32, 18, 16, 384>(wt + T_FQ + p3 * 512 + 64 * sq, wideS, part, tid);
      __syncthreads();
      if (tid < 64) {
        float s = wt[BF + p3 * 512 + 64 * sq + tid];
#pragma unroll
        for (int cs = 0; cs < 32; ++cs) s += part[cs * 64 + tid];
        if (p3 == 0) qhS[tid] = s;
        else if (p3 == 1) kcS[slot * 64 + tid] = s;
        else vcS[slot * 64 + tid] = s;
      }
      __syncthreads();
    }
    // ---- xp slice (residual only) ----
    mvp<32, 18, 16, 128>(wt + T_IN + 64 * sq, wideS, part, tid);
    __syncthreads();
    if (tid < 64) {
      float s = b_in[64 * sq + tid];
#pragma unroll
      for (int cs = 0; cs < 32; ++cs) s += part[cs * 64 + tid];
      xpSl[tid] = s;
    }
    __syncthreads();

    // ---- attention for own head (local) ----
    {
      int st = t - 7 + wv;
      float c = 0.f;
      if (st >= 0) c = qhS[ln] * kcS[(st & 7) * 64 + ln];
      c = wsum(c);
      if (ln == 0) scoresS[wv] = (st >= 0) ? c * 0.125f : -INFINITY;
    }
    __syncthreads();
    if (tid == 0) {
      float mx = -INFINITY;
      for (int j = 0; j < 8; ++j) mx = fmaxf(mx, scoresS[j]);
      float e[8], ssum = 0.f;
      for (int j = 0; j < 8; ++j) { e[j] = expf(scoresS[j] - mx); ssum += e[j]; }
      float inv = 1.f / ssum;
      for (int j = 0; j < 8; ++j) awS[j] = e[j] * inv;
    }
    __syncthreads();
    if (tid < 64) {
      float a = 0.f;
#pragma unroll
      for (int j = 0; j < 8; ++j) {
        int st = t - 7 + j;
        if (st >= 0) a += awS[j] * vcS[(st & 7) * 64 + tid];
      }
      ctxH[tid] = a;
    }
    __syncthreads();

    // ---- stage 0: y partial = W_o[:,head]@ctxH (+ xp slice at own positions) ----
    mvp<4, 16, 128, 128>(wt + T_O + (size_t)64 * sq * 512, ctxH, part, tid);
    __syncthreads();
    {
      float s = 0.f;
#pragma unroll
      for (int cs = 0; cs < 4; ++cs) s += part[cs * 512 + tid];
      if ((tid >> 6) == sq) s += xpSl[tid & 63];
      st_llc(ar + A_YP + sq * 512 + tid, s);
    }
    PUBF(0);
    WAITF(0, t + 1);
    {
      float s = b_o[tid];
#pragma unroll
      for (int q2 = 0; q2 < 8; ++q2) s += ld_llc(ar + A_YP + q2 * 512 + tid);
      yS[tid] = s;
    }
    __syncthreads();
    // ---- LN1 (redundant) ----
    {
      float v = yS[tid];
      float a = wsum(v), b2 = wsum(v * v);
      if (ln == 0) { redA[wv] = a; redB[wv] = b2; }
      __syncthreads();
      float sa = 0.f, sb = 0.f;
#pragma unroll
      for (int i2 = 0; i2 < 8; ++i2) { sa += redA[i2]; sb += redB[i2]; }
      float mu = sa * (1.f / 512.f);
      float var = sb * (1.f / 512.f) - mu * mu;
      float rstd = rsqrtf(var + 1e-5f);
      x2S[tid] = (yS[tid] - mu) * rstd * ln1g[tid] + ln1b[tid];
    }
    __syncthreads();

    // ---- ff1 slice + gelu (local h slice) ----
    mvp<8, 64, 64, 512>(wt + T_FF1 + 256 * sq, x2S, part, tid);
    __syncthreads();
    if (tid < 256) {
      float s = b_ff1[256 * sq + tid];
#pragma unroll
      for (int cs = 0; cs < 8; ++cs) s += part[cs * 256 + tid];
      hSl[tid] = 0.5f * s * (1.f + erff(s * 0.70710678118654752f));
    }
    __syncthreads();

    // ---- stage 1: o partial = W_ff2[:,kslice]@hSl ----
    mvp<4, 64, 128, 128>(wt + T_FF2 + (size_t)256 * sq * 512, hSl, part, tid);
    __syncthreads();
    {
      float s = 0.f;
#pragma unroll
      for (int cs = 0; cs < 4; ++cs) s += part[cs * 512 + tid];
      st_llc(ar + A_OP + sq * 512 + tid, s);
    }
    PUBF(1);
    WAITF(1, t + 1);
    {
      float s = b_ff2[tid] + x2S[tid];
#pragma unroll
      for (int q2 = 0; q2 < 8; ++q2) s += ld_llc(ar + A_OP + q2 * 512 + tid);
      oS[tid] = s;
    }
    __syncthreads();
    // ---- LN2 (redundant) ----
    {
      float v = oS[tid];
      float a = wsum(v), b2 = wsum(v * v);
      if (ln == 0) { redA[wv] = a; redB[wv] = b2; }
      __syncthreads();
      float sa = 0.f, sb = 0.f;
#pragma unroll
      for (int i2 = 0; i2 < 8; ++i2) { sa += redA[i2]; sb += redB[i2]; }
      float mu = sa * (1.f / 512.f);
      float var = sb * (1.f / 512.f) - mu * mu;
      float rstd = rsqrtf(var + 1e-5f);
      onS[tid] = (oS[tid] - mu) * rstd * ln2g[tid] + ln2b[tid];
    }
    __syncthreads();

    // ---- stage 2: rp/wp slice ----
    if (tid < 288) {
      const int cs = tid / 9, g = tid % 9;
      const float4* __restrict__ w4 =
          reinterpret_cast<const float4*>(wt + T_RW + (size_t)(cs * 16) * 288 + 36 * sq) + g;
      const float* __restrict__ v = onS + cs * 16;
      float a0 = 0.f, a1 = 0.f, a2 = 0.f, a3 = 0.f;
#pragma unroll
      for (int c = 0; c < 16; ++c) {
        float4 w = w4[(size_t)c * 72];
        float vv = v[c];
        a0 += vv * w.x; a1 += vv * w.y; a2 += vv * w.z; a3 += vv * w.w;
      }
      *reinterpret_cast<float4*>(part + cs * 36 + g * 4) = make_float4(a0, a1, a2, a3);
    }
    __syncthreads();
    if (tid < 34) {
      int idx = 34 * sq + tid;
      if (idx < 268) {
        float s = (idx < 70) ? b_read[idx] : b_write[idx - 70];
#pragma unroll
        for (int cs = 0; cs < 32; ++cs) s += part[cs * 36 + tid];
        st_llc(ar + A_RWP + idx, s);
      }
    }
    PUBF(2);
    // ---- logits slice (overlaps rwp exchange) ----
    if (tid < 128) {
      const int cs = tid >> 2, g = tid & 3;
      const float4* __restrict__ w4 =
          reinterpret_cast<const float4*>(wt + T_TOK + (size_t)(cs * 16) * 128 + 16 * sq) + g;
      const float* __restrict__ v = onS + cs * 16;
      float a0 = 0.f, a1 = 0.f, a2 = 0.f, a3 = 0.f;
#pragma unroll
      for (int c = 0; c < 16; ++c) {
        float4 w = w4[(size_t)c * 32];
        float vv = v[c];
        a0 += vv * w.x; a1 += vv * w.y; a2 += vv * w.z; a3 += vv * w.w;
      }
      *reinterpret_cast<float4*>(part + tid * 4) = make_float4(a0, a1, a2, a3);
    }
    __syncthreads();
    if (tid < 13) {
      int v = 13 * sq + tid;
      if (v < Vc) {
        float s = b_tok[v];
#pragma unroll
        for (int cs = 0; cs < 32; ++cs) s += part[cs * 16 + tid];
        dout[((size_t)b * Tc + t) * Vc + v] = s;
      }
    }
    WAITF(2, t + 1);
    if (tid < 268) rwpS[tid] = ld_llc(ar + A_RWP + tid);
    __syncthreads();

    // ---- cosine sims: all 128 rows x both keys, local ----
    for (int p = 0; p < 32; ++p) {
      int idx = wv * 32 + p;
      int ksel = idx >> 7, row = idx & 127;
      const float* key = ksel ? (rwpS + 70) : rwpS;
      float m = memS[row * 64 + ln];
      float pp = m * key[ln], qq = m * m;
#pragma unroll
      for (int o = 1; o < 64; o <<= 1) { pp += __shfl_xor(pp, o); qq += __shfl_xor(qq, o); }
      if (ln == 0) cosS[idx] = pp / (sqrtf(qq) + 1e-12f);
    }
    __syncthreads();
    // ---- addressing (waves 0,1) + erase/add precompute (wave 2) ----
    if (wv < 2) {
      const float* P = wv ? (rwpS + 70) : rwpS;
      const float* cosb = cosS + wv * 128;
      float* prevw = wv ? wwvS : rwvS;
      float kk = P[ln];
      float kn2 = wsum(kk * kk);
      float kinv = 1.f / (sqrtf(kn2) + 1e-12f);
      float beta = softplusf_(P[64]);
      float g = sigmoidf_(P[65]);
      float sh0 = P[66], sh1 = P[67], sh2 = P[68];
      float m3 = fmaxf(sh0, fmaxf(sh1, sh2));
      float es0 = expf(sh0 - m3), es1 = expf(sh1 - m3), es2 = expf(sh2 - m3);
      float i3 = 1.f / (es0 + es1 + es2);
      es0 *= i3; es1 *= i3; es2 *= i3;
      float gp = 1.f + softplusf_(P[69]);
      float v0 = beta * cosb[ln] * kinv, v1 = beta * cosb[64 + ln] * kinv;
      float mx = wmax(fmaxf(v0, v1));
      float e0 = expf(v0 - mx), e1 = expf(v1 - mx);
      float einv = 1.f / wsum(e0 + e1);
      float w0 = g * e0 * einv + (1.f - g) * prevw[ln];
      float w1 = g * e1 * einv + (1.f - g) * prevw[64 + ln];
      float w0m = __shfl(w0, (ln + 63) & 63), w1m = __shfl(w1, (ln + 63) & 63);
      float w0p = __shfl(w0, (ln + 1) & 63),  w1p = __shfl(w1, (ln + 1) & 63);
      float prev0 = (ln == 0)  ? w1m : w0m;
      float next0 = (ln == 63) ? w1p : w0p;
      float prev1 = (ln == 0)  ? w0m : w1m;
      float next1 = (ln == 63) ? w0p : w1p;
      float t0 = es0 * next0 + es1 * w0 + es2 * prev0;
      float t1 = es0 * next1 + es1 * w1 + es2 * prev1;
      float wt0 = powf(t0 + 1e-12f, gp), wt1 = powf(t1 + 1e-12f, gp);
      float winv = 1.f / (wsum(wt0 + wt1) + 1e-12f);
      w0 = wt0 * winv; w1 = wt1 * winv;
      prevw[ln] = w0; prevw[64 + ln] = w1;
      if (wv) { wwnS[ln] = w0; wwnS[64 + ln] = w1; }
    } else if (wv == 2) {
      eS[ln] = sigmoidf_(rwpS[140 + ln]);
      aS[ln] = tanhf(rwpS[204 + ln]);
    }
    __syncthreads();
    // ---- memory update (full, replicated) ----
    for (int i = tid; i < 8192; i += 512) {
      int n = i >> 6, m = i & 63;
      float wn = wwnS[n];
      memS[i] = memS[i] * (1.f - wn * eS[m]) + wn * aS[m];
    }
    __syncthreads();
  }
}

extern "C" void kernel_launch(void* const* d_in, const int* in_sizes, int n_in,
                              void* d_out, int out_size, void* d_ws, size_t ws_size,
                              hipStream_t stream) {
  (void)in_sizes; (void)n_in; (void)out_size; (void)ws_size;
  const int* x = (const int*)d_in[0];
  const float* emb = (const float*)d_in[1];
  const float* W_in = (const float*)d_in[2];
  const float* b_in = (const float*)d_in[3];
  const float* W_qkv = (const float*)d_in[4];
  const float* b_qkv = (const float*)d_in[5];
  const float* W_o = (const float*)d_in[6];
  const float* b_o = (const float*)d_in[7];
  const float* ln1g = (const float*)d_in[8];
  const float* ln1b = (const float*)d_in[9];
  const float* W_ff1 = (const float*)d_in[10];
  const float* b_ff1 = (const float*)d_in[11];
  const float* W_ff2 = (const float*)d_in[12];
  const float* b_ff2 = (const float*)d_in[13];
  const float* ln2g = (const float*)d_in[14];
  const float* ln2b = (const float*)d_in[15];
  const float* W_tok = (const float*)d_in[16];
  const float* b_tok = (const float*)d_in[17];
  const float* W_read = (const float*)d_in[18];
  const float* b_read = (const float*)d_in[19];
  const float* W_write = (const float*)d_in[20];
  const float* b_write = (const float*)d_in[21];
  float* ws = (float*)d_ws;
  float* out = (float*)d_out;

  hipLaunchKernelGGL(k_init, dim3(512), dim3(256), 0, stream,
                     W_in, W_qkv, W_o, W_ff1, W_ff2, W_tok, W_read, W_write,
                     b_qkv, b_in, ws);
  hipLaunchKernelGGL(k_fuse, dim3(144), dim3(256), 0, stream, W_qkv, W_in, ws);
  hipLaunchKernelGGL(k_main, dim3(256), dim3(512), 0, stream,
                     x, emb, b_in, b_o, ln1g, ln1b, b_ff1, b_ff2,
                     ln2g, ln2b, b_tok, b_read, b_write, ws, out);
}